// Round 1
// 639.373 us; speedup vs baseline: 1.0494x; 1.0494x over previous
//
#include <hip/hip_runtime.h>
#include <stdint.h>

// MultiheadCorrelation: T=8192, B=4, D=1024, H=16, hd=64. fp32 I/O, bf16 MFMA inside.
// cvt -> gemm8p<0> (A=Wqkv, B=query per-b: writes qT/kT [bh][d][t] natively coalesced)
//     -> gemm8p<1> (v: natural [t*4+b][1024]) -> stats (MFMA partials) -> finalize
//     -> attn (v@corr MFMA) -> gemm8p<2> (fp32 out).
//
// gemm8p = 256x256 tile, BK=64, 512 thr (8 waves 2Mx4N), 8-phase schedule:
//   per K-tile 4 phases (M-half x K-half quadrant, 16 MFMA each), counted
//   vmcnt(4) once per K-tile boundary, setprio(1) around MFMA, raw s_barrier
//   (no __syncthreads -> no vmcnt(0) drain in main loop).
// Staging ledger (per-thread 2 loads per half-tile; halves per tile:
//   q=4t+{0:Ak0,1:Bk0,2:Ak1,3:Bk1}):
//   prologue issues q=0..5, vmcnt(4) -> tile0 fully landed, q4,5 in flight.
//   tile t phases issue q=4t+{6,7,8,9}.  q=4t+8/9 (t+2 Ak0/Bk0) write the
//   CURRENT buffer's k0 regions, whose last readers (P1/P2) are gated by P2's
//   closing barrier before the issue -> race-free with 2 buffers.
//   boundary wait vmcnt(4): newest 4 loads (q=4t+8,9) may fly; all q<=4t+7
//   done => tile t+1 fully landed.  t=14 boundary drains vmcnt(0) (tail).

typedef unsigned short u16;
typedef __attribute__((ext_vector_type(8))) short bf16x8;
typedef __attribute__((ext_vector_type(8))) u16  u16x8;
typedef __attribute__((ext_vector_type(4))) float f32x4;

#define AS1 __attribute__((address_space(1)))
#define AS3 __attribute__((address_space(3)))

__device__ __forceinline__ u16 f2b(float f) {
  union { float f; uint32_t u; } x; x.f = f;
  const uint32_t u = x.u;
  return (u16)((u + 0x7FFFu + ((u >> 16) & 1u)) >> 16);  // RNE
}
__device__ __forceinline__ void g2l16(const void* g, void* l) {
  __builtin_amdgcn_global_load_lds((const AS1 uint32_t*)g, (AS3 uint32_t*)l, 16, 0, 0);
}

// ---------------------------------------------------------------------------
// fused fp32->bf16 convert for query / Wqkv / Wout (one launch)
// ---------------------------------------------------------------------------
__global__ __launch_bounds__(256) void cvt_all(
    const float* __restrict__ q, const float* __restrict__ w1, const float* __restrict__ w2,
    u16* __restrict__ qb, u16* __restrict__ w1b, u16* __restrict__ w2b)
{
  int i = blockIdx.x * 256 + threadIdx.x;
  if (i >= 4718592) return;
  const float* s; u16* d; int ofs;
  if (i < 4194304)      { s = q;  d = qb;  ofs = i; }
  else if (i < 4587520) { s = w1; d = w1b; ofs = i - 4194304; }
  else                  { s = w2; d = w2b; ofs = i - 4587520; }
  const float4 a = *(const float4*)(s + (size_t)ofs * 8);
  const float4 b = *(const float4*)(s + (size_t)ofs * 8 + 4);
  u16x8 o;
  o[0] = f2b(a.x); o[1] = f2b(a.y); o[2] = f2b(a.z); o[3] = f2b(a.w);
  o[4] = f2b(b.x); o[5] = f2b(b.y); o[6] = f2b(b.z); o[7] = f2b(b.w);
  *(u16x8*)(d + (size_t)ofs * 8) = o;
}

// ---------------------------------------------------------------------------
// gemm8p<MODE>: C[m,n] = sum_k A[m,k]*B'[n,k] + bias, K=1024, 256x256 tiles.
// MODE 0: A=Wqkv(2048 rows), B'=query rows (t*4+batch, pitch 4096),
//         out scatter to qkT[seg][(b*16+h)*64+d][8192]. grid 32tn*8tm*4b.
// MODE 1: A [32768,1024], B' [1024,1024], bf16 [M,1024] out. grid 4tn*128tm.
// MODE 2: same as 1 but fp32 out.
// ---------------------------------------------------------------------------
#define BARX() do { asm volatile("" ::: "memory");                    \
                    __builtin_amdgcn_s_barrier();                     \
                    asm volatile("" ::: "memory"); } while (0)

#define LOADA(KH, MH)                                                 \
  _Pragma("unroll") for (int m_ = 0; m_ < 4; ++m_) {                  \
    const int row_ = wr * 128 + (MH) * 64 + m_ * 16 + laneN;          \
    const int sl_ = laneQ ^ ((row_ >> 1) & 3);                        \
    af[m_] = *(const bf16x8*)&As[buf_][KH][row_ * 32 + sl_ * 8];      \
  }

#define LOADB(KH)                                                     \
  _Pragma("unroll") for (int n_ = 0; n_ < 4; ++n_) {                  \
    const int row_ = wc * 64 + n_ * 16 + laneN;                       \
    const int sl_ = laneQ ^ ((row_ >> 1) & 3);                        \
    bf[n_] = *(const bf16x8*)&Bs[buf_][KH][row_ * 32 + sl_ * 8];      \
  }

#define MFMA16(MH)                                                    \
  __builtin_amdgcn_s_setprio(1);                                      \
  _Pragma("unroll") for (int m_ = 0; m_ < 4; ++m_)                    \
    _Pragma("unroll") for (int n_ = 0; n_ < 4; ++n_)                  \
      acc[(MH) * 4 + m_][n_] = __builtin_amdgcn_mfma_f32_16x16x32_bf16( \
          af[m_], bf[n_], acc[(MH) * 4 + m_][n_], 0, 0, 0);           \
  __builtin_amdgcn_s_setprio(0);

#define GTILE(T, TAILWAIT) do {                                       \
    const int buf_ = (T) & 1;                                         \
    bf16x8 af[4], bf[4];                                              \
    LOADA(0, 0) LOADB(0)                                              \
    issue_half(4 * (T) + 6);                                          \
    BARX(); MFMA16(0); BARX();                                        \
    LOADA(0, 1)                                                       \
    issue_half(4 * (T) + 7);                                          \
    BARX(); MFMA16(1); BARX();                                        \
    LOADA(1, 0) LOADB(1)                                              \
    issue_half(4 * (T) + 8);                                          \
    BARX(); MFMA16(0); BARX();                                        \
    LOADA(1, 1)                                                       \
    issue_half(4 * (T) + 9);                                          \
    BARX(); MFMA16(1);                                                \
    TAILWAIT;                                                         \
    BARX();                                                           \
  } while (0)

template <int MODE>
__global__ __launch_bounds__(512, 2) void gemm8p(
    const u16* __restrict__ A, const u16* __restrict__ B,
    const float* __restrict__ bias, void* __restrict__ OutP)
{
  __shared__ __align__(16) u16 As[2][2][8192];   // [dbuf][k-half][256 rows x 32]
  __shared__ __align__(16) u16 Bs[2][2][8192];
  const int tid = threadIdx.x;
  int bn, bm, batch;
  if (MODE == 0) { bn = blockIdx.x & 31; bm = (blockIdx.x >> 5) & 7; batch = blockIdx.x >> 8; }
  else           { bn = blockIdx.x & 3;  bm = blockIdx.x >> 2;       batch = 0; }
  const int m0 = bm * 256, n0 = bn * 256;
  const int lane = tid & 63, wave = tid >> 6;
  const int wr = wave >> 2, wc = wave & 3;     // 2M x 4N wave grid
  const int laneN = lane & 15, laneQ = lane >> 4;

  const u16* Abase = A + (size_t)m0 * 1024;
  const size_t bPitch = (MODE == 0) ? 4096 : 1024;
  const u16* Bbase = (MODE == 0) ? (B + (size_t)batch * 1024 + (size_t)n0 * 4096)
                                 : (B + (size_t)n0 * 1024);

  // staging: half-tile = 256 rows x 32 k-cols (16 KB); thread covers rows
  // sr and sr+128 at 16B slot sl; source pre-swizzled so LDS dest is linear.
  const int sr = tid >> 2, sl = tid & 3;
  const int qg = sl ^ ((sr >> 1) & 3);
  const size_t aofs0 = (size_t)sr * 1024 + qg * 8;
  const size_t aofs1 = aofs0 + (size_t)128 * 1024;
  const size_t bofs0 = (size_t)sr * bPitch + qg * 8;
  const size_t bofs1 = bofs0 + (size_t)128 * bPitch;

  auto issue_half = [&](int q) {
    if (q >= 64) return;
    const int tq = q >> 2, ty = q & 3;
    const int bufq = tq & 1, kh = ty >> 1;
    const int kofs = tq * 64 + kh * 32;
    if ((ty & 1) == 0) {
      u16* l = &As[bufq][kh][tid * 8];
      g2l16(Abase + aofs0 + kofs, l);
      g2l16(Abase + aofs1 + kofs, l + 4096);
    } else {
      u16* l = &Bs[bufq][kh][tid * 8];
      g2l16(Bbase + bofs0 + kofs, l);
      g2l16(Bbase + bofs1 + kofs, l + 4096);
    }
  };

  f32x4 acc[8][4] = {};

  // prologue: tile0 all 4 halves + tile1 Ak0,Bk0; wait tile0 landed.
#pragma unroll
  for (int q = 0; q < 6; ++q) issue_half(q);
  asm volatile("s_waitcnt vmcnt(4)" ::: "memory");
  __builtin_amdgcn_s_barrier();
  asm volatile("" ::: "memory");

#pragma unroll 2
  for (int t = 0; t < 14; ++t)
    GTILE(t, asm volatile("s_waitcnt vmcnt(4)" ::: "memory"));
  GTILE(14, asm volatile("s_waitcnt vmcnt(0)" ::: "memory"));
  GTILE(15, (void)0);

  if (MODE == 0) {
#pragma unroll
    for (int m = 0; m < 8; ++m) {
#pragma unroll
      for (int r = 0; r < 4; ++r) {
        const int f = m0 + wr * 128 + m * 16 + laneQ * 4 + r;
        const float bv = bias[f];
        const int seg = f >> 10, h = (f & 1023) >> 6, d = f & 63;
        u16* base = (u16*)OutP + (size_t)seg * 33554432 +
                    ((size_t)((batch * 16 + h) * 64 + d)) * 8192;
#pragma unroll
        for (int n = 0; n < 4; ++n) {
          const int t = n0 + wc * 64 + n * 16 + laneN;
          base[t] = f2b(acc[m][n][r] + bv);
        }
      }
    }
  } else {
#pragma unroll
    for (int m = 0; m < 8; ++m) {
#pragma unroll
      for (int n = 0; n < 4; ++n) {
        const int col = n0 + wc * 64 + n * 16 + laneN;
        const float bv = bias[col];
#pragma unroll
        for (int r = 0; r < 4; ++r) {
          const int row = m0 + wr * 128 + m * 16 + laneQ * 4 + r;
          const float v = acc[m][n][r] + bv;
          if (MODE == 1) ((u16*)OutP)[(size_t)row * 1024 + col] = f2b(v);
          else           ((float*)OutP)[(size_t)row * 1024 + col] = v;
        }
      }
    }
  }
}

#undef GTILE
#undef MFMA16
#undef LOADB
#undef LOADA
#undef BARX

// ---------------------------------------------------------------------------
// Stats (MFMA): per (b,h) S[d][e]=sum_t q_d k_e, plus Sq,Sqq,Sk,Skk.
// qT,kT: [bh][64 d][8192 t] bf16. grid = 64 bh * 8 chunks, block 256.
// ---------------------------------------------------------------------------
__global__ __launch_bounds__(256) void stats_k(
    const u16* __restrict__ qT, const u16* __restrict__ kT,
    float* __restrict__ Spart, float* __restrict__ Mpart)
{
  __shared__ __align__(16) u16 smem[2 * 4 * 64 * 64];  // 64 KB
  __shared__ float margLDS[4 * 256];
  u16* Qs = smem;
  u16* Ks = smem + 16384;
  const int tid = threadIdx.x;
  const int bh = blockIdx.x & 63;
  const int chunk = blockIdx.x >> 6;
  const int t0 = chunk * 1024;
  const int lane = tid & 63, wave = tid >> 6;
  const int laneN = lane & 15, laneQ = lane >> 4;

  const u16* qp = qT + (size_t)bh * 524288;
  const u16* kp = kT + (size_t)bh * 524288;

  f32x4 accS[4][4] = {};
  f32x4 accQQ[4] = {}, accKK[4] = {}, accQ1[4] = {}, accK1[4] = {};
  bf16x8 ones;
#pragma unroll
  for (int j = 0; j < 8; ++j) ones[j] = (short)0x3F80;

  for (int rd = 0; rd < 4; ++rd) {
    __syncthreads();
#pragma unroll
    for (int i = 0; i < 8; ++i) {
      const int c = tid + i * 256;
      const int tile = c >> 9, cw = c & 511;
      const int d = cw >> 3, slot = cw & 7;
      const int kb = slot ^ (d & 7);
      const size_t gofs = (size_t)d * 8192 + (t0 + rd * 256 + tile * 64 + kb * 8);
      g2l16(qp + gofs, &Qs[c * 8]);
      g2l16(kp + gofs, &Ks[c * 8]);
    }
    __syncthreads();
    const u16* qt = &Qs[wave * 4096];
    const u16* kt2 = &Ks[wave * 4096];
#pragma unroll
    for (int ks2 = 0; ks2 < 2; ++ks2) {
      bf16x8 qf[4], kf[4];
#pragma unroll
      for (int i = 0; i < 4; ++i) {
        const int d = i * 16 + laneN;
        const int kq = (ks2 * 4 + laneQ) ^ (d & 7);
        qf[i] = *(const bf16x8*)&qt[d * 64 + kq * 8];
        kf[i] = *(const bf16x8*)&kt2[d * 64 + kq * 8];
      }
#pragma unroll
      for (int i = 0; i < 4; ++i) {
#pragma unroll
        for (int j = 0; j < 4; ++j)
          accS[i][j] = __builtin_amdgcn_mfma_f32_16x16x32_bf16(qf[i], kf[j], accS[i][j], 0, 0, 0);
        accQQ[i] = __builtin_amdgcn_mfma_f32_16x16x32_bf16(qf[i], qf[i], accQQ[i], 0, 0, 0);
        accKK[i] = __builtin_amdgcn_mfma_f32_16x16x32_bf16(kf[i], kf[i], accKK[i], 0, 0, 0);
        accQ1[i] = __builtin_amdgcn_mfma_f32_16x16x32_bf16(qf[i], ones, accQ1[i], 0, 0, 0);
        accK1[i] = __builtin_amdgcn_mfma_f32_16x16x32_bf16(kf[i], ones, accK1[i], 0, 0, 0);
      }
    }
  }

  __syncthreads();
  float* red = (float*)smem;
#pragma unroll
  for (int i = 0; i < 4; ++i)
#pragma unroll
    for (int j = 0; j < 4; ++j)
#pragma unroll
      for (int r = 0; r < 4; ++r) {
        const int d = i * 16 + laneQ * 4 + r, e = j * 16 + laneN;
        red[wave * 4096 + d * 64 + e] = accS[i][j][r];
      }
#pragma unroll
  for (int i = 0; i < 4; ++i) {
    if (laneN == 0) {
#pragma unroll
      for (int r = 0; r < 4; ++r) {
        const int d = i * 16 + laneQ * 4 + r;
        margLDS[wave * 256 + 0 * 64 + d] = accQ1[i][r];
        margLDS[wave * 256 + 2 * 64 + d] = accK1[i][r];
      }
    }
    if ((laneN >> 2) == laneQ) {
      const int r = laneN & 3;
      const int d = i * 16 + laneN;
      margLDS[wave * 256 + 1 * 64 + d] = accQQ[i][r];
      margLDS[wave * 256 + 3 * 64 + d] = accKK[i][r];
    }
  }
  __syncthreads();
  float* Sp = Spart + ((size_t)chunk * 64 + bh) * 4096;
  for (int c = tid; c < 4096; c += 256)
    Sp[c] = red[c] + red[4096 + c] + red[8192 + c] + red[12288 + c];
  float* Mp = Mpart + ((size_t)chunk * 64 + bh) * 256;
  Mp[tid] = margLDS[tid] + margLDS[256 + tid] + margLDS[512 + tid] + margLDS[768 + tid];
}

// ---------------------------------------------------------------------------
// Finalize: sum partials; corr=clip(cov/sqrt(sx sy),0,1); softmax over d;
// store corrT[e][d] bf16. grid 64 (bh), block 64 (e).
// ---------------------------------------------------------------------------
__global__ __launch_bounds__(64) void finalize_k(
    const float* __restrict__ Spart, const float* __restrict__ Mpart,
    u16* __restrict__ corrT)
{
  __shared__ float Ss[4096];
  __shared__ float sqs[64], sxs[64];
  const int bh = blockIdx.x;
  const int e = threadIdx.x;
  for (int idx = e; idx < 4096; idx += 64) {
    float s = 0.f;
#pragma unroll
    for (int c = 0; c < 8; ++c) s += Spart[((size_t)c * 64 + bh) * 4096 + idx];
    Ss[idx] = s;
  }
  float m[4];
#pragma unroll
  for (int p = 0; p < 4; ++p) {
    float s = 0.f;
#pragma unroll
    for (int c = 0; c < 8; ++c) s += Mpart[((size_t)c * 64 + bh) * 256 + p * 64 + e];
    m[p] = s;
  }
  const float invT = 1.0f / 8192.0f;
  const float sy = m[3] - m[2] * m[2] * invT;
  const float ske = m[2];
  sqs[e] = m[0];
  sxs[e] = m[1] - m[0] * m[0] * invT;
  __syncthreads();
  float mx = 0.0f;
  for (int d = 0; d < 64; ++d) {
    const float c = Ss[d * 64 + e] - sqs[d] * ske * invT;
    float r = c / sqrtf(sxs[d] * sy);
    r = fminf(fmaxf(r, 0.0f), 1.0f);
    Ss[d * 64 + e] = r;
    mx = fmaxf(mx, r);
  }
  float sum = 0.f;
  for (int d = 0; d < 64; ++d) {
    const float ev = expf(Ss[d * 64 + e] - mx);
    Ss[d * 64 + e] = ev;
    sum += ev;
  }
  const float inv = 1.0f / sum;
  for (int d = 0; d < 64; ++d)
    corrT[(size_t)bh * 4096 + e * 64 + d] = f2b(Ss[d * 64 + e] * inv);
}

// ---------------------------------------------------------------------------
// Attn: attn[t,e] = sum_d v[t,d]*corr[d,e] per (b,h). A=v natural, B^T=corrT.
// grid = 64 bh * 32 t-tiles(256), block 256.
// ---------------------------------------------------------------------------
__global__ __launch_bounds__(256) void attn_k(
    const u16* __restrict__ vb, const u16* __restrict__ corrT,
    u16* __restrict__ attnb)
{
  __shared__ __align__(16) u16 Vs[256 * 64];
  __shared__ __align__(16) u16 Cs[64 * 64];
  const int tid = threadIdx.x;
  const int bh = blockIdx.x & 63;
  const int tt0 = (blockIdx.x >> 6) * 256;
  const int b = bh >> 4, h = bh & 15;
  const int lane = tid & 63, wave = tid >> 6;
  const int laneN = lane & 15, laneQ = lane >> 4;

  {
#pragma unroll
    for (int i = 0; i < 8; ++i) {
      const int c = tid + i * 256;
      const int row = c >> 3, slot = c & 7;
      const int kb = slot ^ (row & 7);
      const u16* g = vb + (size_t)((tt0 + row) * 4 + b) * 1024 + h * 64 + kb * 8;
      g2l16(g, &Vs[c * 8]);
    }
#pragma unroll
    for (int i = 0; i < 2; ++i) {
      const int c = tid + i * 256;
      const int row = c >> 3, slot = c & 7;
      const int kb = slot ^ (row & 7);
      g2l16(corrT + (size_t)bh * 4096 + row * 64 + kb * 8, &Cs[c * 8]);
    }
  }
  __syncthreads();

  const int wt = wave * 64;
  f32x4 acc[4][4] = {};
#pragma unroll
  for (int ks2 = 0; ks2 < 2; ++ks2) {
    bf16x8 af[4], bf[4];
#pragma unroll
    for (int i = 0; i < 4; ++i) {
      const int row = wt + i * 16 + laneN;
      const int kq = (ks2 * 4 + laneQ) ^ (row & 7);
      af[i] = *(const bf16x8*)&Vs[row * 64 + kq * 8];
    }
#pragma unroll
    for (int j = 0; j < 4; ++j) {
      const int row = j * 16 + laneN;
      const int kq = (ks2 * 4 + laneQ) ^ (row & 7);
      bf[j] = *(const bf16x8*)&Cs[row * 64 + kq * 8];
    }
#pragma unroll
    for (int i = 0; i < 4; ++i)
#pragma unroll
      for (int j = 0; j < 4; ++j)
        acc[i][j] = __builtin_amdgcn_mfma_f32_16x16x32_bf16(af[i], bf[j], acc[i][j], 0, 0, 0);
  }
#pragma unroll
  for (int i = 0; i < 4; ++i)
#pragma unroll
    for (int j = 0; j < 4; ++j)
#pragma unroll
      for (int r = 0; r < 4; ++r) {
        const int t = tt0 + wt + i * 16 + laneQ * 4 + r;
        const int e = j * 16 + laneN;
        attnb[(size_t)(t * 4 + b) * 1024 + h * 64 + e] = f2b(acc[i][j][r]);
      }
}

// ---------------------------------------------------------------------------
// ws layout (bytes):
//   0          qT   [64bh][64][8192] bf16 (64 MiB) -> reused as attn out [32768][1024]
//   67108864   kT   (64 MiB)
//   134217728  vb   [32768][1024] bf16 (64 MiB)
//   201326592  queryb (64 MiB)  -- dead after gemms, aliased by:
//     201326592  Spart 8*64*4096 f32 (8 MiB)
//     209715200  Mpart 8*64*256 f32 (512 KiB)
//     210239488  corrT 64*4096 bf16 (512 KiB)
//   268435456  Wqkvb (6 MiB)
//   274726912  Woutb (2 MiB)
// ---------------------------------------------------------------------------
extern "C" void kernel_launch(void* const* d_in, const int* in_sizes, int n_in,
                              void* d_out, int out_size, void* d_ws, size_t ws_size,
                              hipStream_t stream)
{
  const float* query = (const float*)d_in[0];
  const float* Wqkv  = (const float*)d_in[1];
  const float* bqkv  = (const float*)d_in[2];
  const float* Wout  = (const float*)d_in[3];
  const float* bout  = (const float*)d_in[4];
  char* ws = (char*)d_ws;

  u16*   qkT    = (u16*)(ws);                 // q seg then k seg
  u16*   kT     = (u16*)(ws + 67108864);
  u16*   vb     = (u16*)(ws + 134217728);
  u16*   queryb = (u16*)(ws + 201326592);
  float* Spart  = (float*)(ws + 201326592);
  float* Mpart  = (float*)(ws + 209715200);
  u16*   corrT  = (u16*)(ws + 210239488);
  u16*   Wqkvb  = (u16*)(ws + 268435456);
  u16*   Woutb  = (u16*)(ws + 274726912);

  cvt_all<<<dim3(18432), dim3(256), 0, stream>>>(query, Wqkv, Wout, queryb, Wqkvb, Woutb);

  // q,k features (2048) in swapped orientation -> [bh][d][t] natively
  gemm8p<0><<<dim3(1024), dim3(512), 0, stream>>>(Wqkvb, queryb, bqkv, qkT);
  // v features (1024) in original orientation -> natural [t*4+b][1024]
  gemm8p<1><<<dim3(512), dim3(512), 0, stream>>>(queryb, Wqkvb + (size_t)2048 * 1024,
                                                 bqkv + 2048, vb);
  stats_k<<<dim3(512), dim3(256), 0, stream>>>(qkT, kT, Spart, Mpart);
  finalize_k<<<dim3(64), dim3(64), 0, stream>>>(Spart, Mpart, corrT);
  attn_k<<<dim3(2048), dim3(256), 0, stream>>>(vb, corrT, qkT);
  gemm8p<2><<<dim3(512), dim3(512), 0, stream>>>(qkT, Woutb, bout, d_out);
}

// Round 2
// 617.164 us; speedup vs baseline: 1.0872x; 1.0360x over previous
//
#include <hip/hip_runtime.h>
#include <stdint.h>

// MultiheadCorrelation: T=8192, B=4, D=1024, H=16, hd=64. fp32 I/O, bf16 MFMA inside.
// cvt -> gemm8p<0> (A=Wqkv, B=query per-b: writes qT/kT [bh][d][t] natively coalesced)
//     -> gemm8p<1> (v: natural [t*4+b][1024]) -> stats (MFMA partials) -> finalize
//     -> attn (v@corr MFMA) -> gemm8p<2> (fp32 out).
//
// gemm8p = 256x256 tile, BK=64, 512 thr (8 waves 2Mx4N), 8-phase schedule with
// COUNTED-LGKM fine-grain interleave: ds_reads issued via pinned-order inline
// asm before each barrier; after the barrier a descending lgkmcnt(3/2/1/0)
// ladder releases one A-frag per 4-MFMA group so the LDS drain overlaps MFMA.
// sched_barrier(0) after every counted wait (rule: compiler hoists reg-only
// MFMA past asm waits otherwise).
// Staging ledger (per-thread 2 loads per half-tile; halves per tile:
//   q=4t+{0:Ak0,1:Bk0,2:Ak1,3:Bk1}):
//   prologue issues q=0..5, vmcnt(4) -> tile0 fully landed, q4,5 in flight.
//   tile t phases issue q=4t+{6,7,8,9}.  Boundary vmcnt(4) at end of tile t
//   => all q<=4t+7 done => tile t+1 fully landed. q=4t+8/9 overwrite the
//   CURRENT buffer's k0 regions whose last readers drained (lgkmcnt(0))
//   before the preceding barrier -> race-free with 2 buffers.
//   t=14 boundary drains vmcnt(0) (tail).

typedef unsigned short u16;
typedef __attribute__((ext_vector_type(8))) short bf16x8;
typedef __attribute__((ext_vector_type(8))) u16  u16x8;
typedef __attribute__((ext_vector_type(4))) float f32x4;

#define AS1 __attribute__((address_space(1)))
#define AS3 __attribute__((address_space(3)))

__device__ __forceinline__ u16 f2b(float f) {
  union { float f; uint32_t u; } x; x.f = f;
  const uint32_t u = x.u;
  return (u16)((u + 0x7FFFu + ((u >> 16) & 1u)) >> 16);  // RNE
}
__device__ __forceinline__ void g2l16(const void* g, void* l) {
  __builtin_amdgcn_global_load_lds((const AS1 uint32_t*)g, (AS3 uint32_t*)l, 16, 0, 0);
}
// pinned-order LDS read (byte address in LDS space)
__device__ __forceinline__ bf16x8 lds_read16(uint32_t addr) {
  bf16x8 r;
  asm volatile("ds_read_b128 %0, %1" : "=&v"(r) : "v"(addr) : "memory");
  return r;
}

// ---------------------------------------------------------------------------
// fused fp32->bf16 convert for query / Wqkv / Wout (one launch)
// ---------------------------------------------------------------------------
__global__ __launch_bounds__(256) void cvt_all(
    const float* __restrict__ q, const float* __restrict__ w1, const float* __restrict__ w2,
    u16* __restrict__ qb, u16* __restrict__ w1b, u16* __restrict__ w2b)
{
  int i = blockIdx.x * 256 + threadIdx.x;
  if (i >= 4718592) return;
  const float* s; u16* d; int ofs;
  if (i < 4194304)      { s = q;  d = qb;  ofs = i; }
  else if (i < 4587520) { s = w1; d = w1b; ofs = i - 4194304; }
  else                  { s = w2; d = w2b; ofs = i - 4587520; }
  const float4 a = *(const float4*)(s + (size_t)ofs * 8);
  const float4 b = *(const float4*)(s + (size_t)ofs * 8 + 4);
  u16x8 o;
  o[0] = f2b(a.x); o[1] = f2b(a.y); o[2] = f2b(a.z); o[3] = f2b(a.w);
  o[4] = f2b(b.x); o[5] = f2b(b.y); o[6] = f2b(b.z); o[7] = f2b(b.w);
  *(u16x8*)(d + (size_t)ofs * 8) = o;
}

// ---------------------------------------------------------------------------
// gemm8p<MODE>: C[m,n] = sum_k A[m,k]*B'[n,k] + bias, K=1024, 256x256 tiles.
// MODE 0: A=Wqkv(2048 rows), B'=query rows (t*4+batch, pitch 4096),
//         out scatter to qkT[seg][(b*16+h)*64+d][8192]. grid 32tn*8tm*4b.
// MODE 1: A [32768,1024], B' [1024,1024], bf16 [M,1024] out. grid 4tn*128tm.
// MODE 2: same as 1 but fp32 out.
// ---------------------------------------------------------------------------
#define BARX() do { asm volatile("" ::: "memory");                    \
                    __builtin_amdgcn_s_barrier();                     \
                    asm volatile("" ::: "memory"); } while (0)

#define WAITDS(N) do {                                                \
    asm volatile("s_waitcnt lgkmcnt(" #N ")" ::: "memory");           \
    __builtin_amdgcn_sched_barrier(0); } while (0)

#define MROW(MH, M_)                                                  \
  _Pragma("unroll") for (int n_ = 0; n_ < 4; ++n_)                    \
    acc[(MH) * 4 + (M_)][n_] = __builtin_amdgcn_mfma_f32_16x16x32_bf16( \
        af[M_], bf[n_], acc[(MH) * 4 + (M_)][n_], 0, 0, 0);

// even phase: fresh bf (4 reads) + af MH=0 (4 reads); ladder 3/2/1/0.
#define PH_EVEN(BUF, KH, Q) do {                                      \
    const uint32_t qo_ = ((BUF) * 2 + (KH)) * 16384u;                 \
    bf[0] = lds_read16(boffB[0] + qo_);                               \
    bf[1] = lds_read16(boffB[1] + qo_);                               \
    bf[2] = lds_read16(boffB[2] + qo_);                               \
    bf[3] = lds_read16(boffB[3] + qo_);                               \
    af[0] = lds_read16(aoffB[0][0] + qo_);                            \
    af[1] = lds_read16(aoffB[0][1] + qo_);                            \
    af[2] = lds_read16(aoffB[0][2] + qo_);                            \
    af[3] = lds_read16(aoffB[0][3] + qo_);                            \
    issue_half(Q);                                                    \
    BARX();                                                           \
    WAITDS(3); __builtin_amdgcn_s_setprio(1); MROW(0, 0);             \
    WAITDS(2); MROW(0, 1);                                            \
    WAITDS(1); MROW(0, 2);                                            \
    WAITDS(0); MROW(0, 3); __builtin_amdgcn_s_setprio(0);             \
    BARX();                                                           \
  } while (0)

// odd phase: reuse bf; af MH=1 (4 reads); ladder 3/2/1/0.
#define PH_ODD(BUF, KH, Q, TAILWAIT) do {                             \
    const uint32_t qo_ = ((BUF) * 2 + (KH)) * 16384u;                 \
    af[0] = lds_read16(aoffB[1][0] + qo_);                            \
    af[1] = lds_read16(aoffB[1][1] + qo_);                            \
    af[2] = lds_read16(aoffB[1][2] + qo_);                            \
    af[3] = lds_read16(aoffB[1][3] + qo_);                            \
    issue_half(Q);                                                    \
    BARX();                                                           \
    WAITDS(3); __builtin_amdgcn_s_setprio(1); MROW(1, 0);             \
    WAITDS(2); MROW(1, 1);                                            \
    WAITDS(1); MROW(1, 2);                                            \
    WAITDS(0); MROW(1, 3); __builtin_amdgcn_s_setprio(0);             \
    TAILWAIT;                                                         \
    BARX();                                                           \
  } while (0)

#define GTILE(T, TAILWAIT) do {                                       \
    const int buf_ = (T) & 1;                                         \
    PH_EVEN(buf_, 0, 4 * (T) + 6);                                    \
    PH_ODD (buf_, 0, 4 * (T) + 7, (void)0);                           \
    PH_EVEN(buf_, 1, 4 * (T) + 8);                                    \
    PH_ODD (buf_, 1, 4 * (T) + 9, TAILWAIT);                          \
  } while (0)

template <int MODE>
__global__ __launch_bounds__(512, 2) void gemm8p(
    const u16* __restrict__ A, const u16* __restrict__ B,
    const float* __restrict__ bias, void* __restrict__ OutP)
{
  __shared__ __align__(16) u16 As[2][2][8192];   // [dbuf][k-half][256 rows x 32]
  __shared__ __align__(16) u16 Bs[2][2][8192];
  const int tid = threadIdx.x;
  int bn, bm, batch;
  if (MODE == 0) { bn = blockIdx.x & 31; bm = (blockIdx.x >> 5) & 7; batch = blockIdx.x >> 8; }
  else           { bn = blockIdx.x & 3;  bm = blockIdx.x >> 2;       batch = 0; }
  const int m0 = bm * 256, n0 = bn * 256;
  const int lane = tid & 63, wave = tid >> 6;
  const int wr = wave >> 2, wc = wave & 3;     // 2M x 4N wave grid
  const int laneN = lane & 15, laneQ = lane >> 4;

  const u16* Abase = A + (size_t)m0 * 1024;
  const size_t bPitch = (MODE == 0) ? 4096 : 1024;
  const u16* Bbase = (MODE == 0) ? (B + (size_t)batch * 1024 + (size_t)n0 * 4096)
                                 : (B + (size_t)n0 * 1024);

  // precomputed absolute LDS byte addresses (within quarter 0) for frag reads
  const uint32_t AsB = (uint32_t)(uintptr_t)(const AS3 u16*)&As[0][0][0];
  const uint32_t BsB = (uint32_t)(uintptr_t)(const AS3 u16*)&Bs[0][0][0];
  uint32_t aoffB[2][4], boffB[4];
#pragma unroll
  for (int mh = 0; mh < 2; ++mh)
#pragma unroll
    for (int m = 0; m < 4; ++m) {
      const int row = wr * 128 + mh * 64 + m * 16 + laneN;
      const int sl = laneQ ^ ((row >> 1) & 3);
      aoffB[mh][m] = AsB + (uint32_t)(row * 64 + sl * 16);
    }
#pragma unroll
  for (int n = 0; n < 4; ++n) {
    const int row = wc * 64 + n * 16 + laneN;
    const int sl = laneQ ^ ((row >> 1) & 3);
    boffB[n] = BsB + (uint32_t)(row * 64 + sl * 16);
  }

  // staging: half-tile = 256 rows x 32 k-cols (16 KB); thread covers rows
  // sr and sr+128 at 16B slot sl; source pre-swizzled so LDS dest is linear.
  const int sr = tid >> 2, sl = tid & 3;
  const int qg = sl ^ ((sr >> 1) & 3);
  const size_t aofs0 = (size_t)sr * 1024 + qg * 8;
  const size_t aofs1 = aofs0 + (size_t)128 * 1024;
  const size_t bofs0 = (size_t)sr * bPitch + qg * 8;
  const size_t bofs1 = bofs0 + (size_t)128 * bPitch;

  auto issue_half = [&](int q) {
    if (q >= 64) return;
    const int tq = q >> 2, ty = q & 3;
    const int bufq = tq & 1, kh = ty >> 1;
    const int kofs = tq * 64 + kh * 32;
    if ((ty & 1) == 0) {
      u16* l = &As[bufq][kh][tid * 8];
      g2l16(Abase + aofs0 + kofs, l);
      g2l16(Abase + aofs1 + kofs, l + 4096);
    } else {
      u16* l = &Bs[bufq][kh][tid * 8];
      g2l16(Bbase + bofs0 + kofs, l);
      g2l16(Bbase + bofs1 + kofs, l + 4096);
    }
  };

  f32x4 acc[8][4] = {};
  bf16x8 af[4], bf[4];

  // prologue: tile0 all 4 halves + tile1 Ak0,Bk0; wait tile0 landed.
#pragma unroll
  for (int q = 0; q < 6; ++q) issue_half(q);
  asm volatile("s_waitcnt vmcnt(4)" ::: "memory");
  __builtin_amdgcn_s_barrier();
  asm volatile("" ::: "memory");

#pragma unroll 2
  for (int t = 0; t < 14; ++t)
    GTILE(t, asm volatile("s_waitcnt vmcnt(4)" ::: "memory"));
  GTILE(14, asm volatile("s_waitcnt vmcnt(0)" ::: "memory"));
  GTILE(15, (void)0);

  if (MODE == 0) {
#pragma unroll
    for (int m = 0; m < 8; ++m) {
#pragma unroll
      for (int r = 0; r < 4; ++r) {
        const int f = m0 + wr * 128 + m * 16 + laneQ * 4 + r;
        const float bv = bias[f];
        const int seg = f >> 10, h = (f & 1023) >> 6, d = f & 63;
        u16* base = (u16*)OutP + (size_t)seg * 33554432 +
                    ((size_t)((batch * 16 + h) * 64 + d)) * 8192;
#pragma unroll
        for (int n = 0; n < 4; ++n) {
          const int t = n0 + wc * 64 + n * 16 + laneN;
          base[t] = f2b(acc[m][n][r] + bv);
        }
      }
    }
  } else {
#pragma unroll
    for (int m = 0; m < 8; ++m) {
#pragma unroll
      for (int n = 0; n < 4; ++n) {
        const int col = n0 + wc * 64 + n * 16 + laneN;
        const float bv = bias[col];
#pragma unroll
        for (int r = 0; r < 4; ++r) {
          const int row = m0 + wr * 128 + m * 16 + laneQ * 4 + r;
          const float v = acc[m][n][r] + bv;
          if (MODE == 1) ((u16*)OutP)[(size_t)row * 1024 + col] = f2b(v);
          else           ((float*)OutP)[(size_t)row * 1024 + col] = v;
        }
      }
    }
  }
}

#undef GTILE
#undef PH_ODD
#undef PH_EVEN
#undef MROW
#undef WAITDS
#undef BARX

// ---------------------------------------------------------------------------
// Stats (MFMA): per (b,h) S[d][e]=sum_t q_d k_e, plus Sq,Sqq,Sk,Skk.
// qT,kT: [bh][64 d][8192 t] bf16. grid = 64 bh * 8 chunks, block 256.
// ---------------------------------------------------------------------------
__global__ __launch_bounds__(256) void stats_k(
    const u16* __restrict__ qT, const u16* __restrict__ kT,
    float* __restrict__ Spart, float* __restrict__ Mpart)
{
  __shared__ __align__(16) u16 smem[2 * 4 * 64 * 64];  // 64 KB
  __shared__ float margLDS[4 * 256];
  u16* Qs = smem;
  u16* Ks = smem + 16384;
  const int tid = threadIdx.x;
  const int bh = blockIdx.x & 63;
  const int chunk = blockIdx.x >> 6;
  const int t0 = chunk * 1024;
  const int lane = tid & 63, wave = tid >> 6;
  const int laneN = lane & 15, laneQ = lane >> 4;

  const u16* qp = qT + (size_t)bh * 524288;
  const u16* kp = kT + (size_t)bh * 524288;

  f32x4 accS[4][4] = {};
  f32x4 accQQ[4] = {}, accKK[4] = {}, accQ1[4] = {}, accK1[4] = {};
  bf16x8 ones;
#pragma unroll
  for (int j = 0; j < 8; ++j) ones[j] = (short)0x3F80;

  for (int rd = 0; rd < 4; ++rd) {
    __syncthreads();
#pragma unroll
    for (int i = 0; i < 8; ++i) {
      const int c = tid + i * 256;
      const int tile = c >> 9, cw = c & 511;
      const int d = cw >> 3, slot = cw & 7;
      const int kb = slot ^ (d & 7);
      const size_t gofs = (size_t)d * 8192 + (t0 + rd * 256 + tile * 64 + kb * 8);
      g2l16(qp + gofs, &Qs[c * 8]);
      g2l16(kp + gofs, &Ks[c * 8]);
    }
    __syncthreads();
    const u16* qt = &Qs[wave * 4096];
    const u16* kt2 = &Ks[wave * 4096];
#pragma unroll
    for (int ks2 = 0; ks2 < 2; ++ks2) {
      bf16x8 qf[4], kf[4];
#pragma unroll
      for (int i = 0; i < 4; ++i) {
        const int d = i * 16 + laneN;
        const int kq = (ks2 * 4 + laneQ) ^ (d & 7);
        qf[i] = *(const bf16x8*)&qt[d * 64 + kq * 8];
        kf[i] = *(const bf16x8*)&kt2[d * 64 + kq * 8];
      }
#pragma unroll
      for (int i = 0; i < 4; ++i) {
#pragma unroll
        for (int j = 0; j < 4; ++j)
          accS[i][j] = __builtin_amdgcn_mfma_f32_16x16x32_bf16(qf[i], kf[j], accS[i][j], 0, 0, 0);
        accQQ[i] = __builtin_amdgcn_mfma_f32_16x16x32_bf16(qf[i], qf[i], accQQ[i], 0, 0, 0);
        accKK[i] = __builtin_amdgcn_mfma_f32_16x16x32_bf16(kf[i], kf[i], accKK[i], 0, 0, 0);
        accQ1[i] = __builtin_amdgcn_mfma_f32_16x16x32_bf16(qf[i], ones, accQ1[i], 0, 0, 0);
        accK1[i] = __builtin_amdgcn_mfma_f32_16x16x32_bf16(kf[i], ones, accK1[i], 0, 0, 0);
      }
    }
  }

  __syncthreads();
  float* red = (float*)smem;
#pragma unroll
  for (int i = 0; i < 4; ++i)
#pragma unroll
    for (int j = 0; j < 4; ++j)
#pragma unroll
      for (int r = 0; r < 4; ++r) {
        const int d = i * 16 + laneQ * 4 + r, e = j * 16 + laneN;
        red[wave * 4096 + d * 64 + e] = accS[i][j][r];
      }
#pragma unroll
  for (int i = 0; i < 4; ++i) {
    if (laneN == 0) {
#pragma unroll
      for (int r = 0; r < 4; ++r) {
        const int d = i * 16 + laneQ * 4 + r;
        margLDS[wave * 256 + 0 * 64 + d] = accQ1[i][r];
        margLDS[wave * 256 + 2 * 64 + d] = accK1[i][r];
      }
    }
    if ((laneN >> 2) == laneQ) {
      const int r = laneN & 3;
      const int d = i * 16 + laneN;
      margLDS[wave * 256 + 1 * 64 + d] = accQQ[i][r];
      margLDS[wave * 256 + 3 * 64 + d] = accKK[i][r];
    }
  }
  __syncthreads();
  float* Sp = Spart + ((size_t)chunk * 64 + bh) * 4096;
  for (int c = tid; c < 4096; c += 256)
    Sp[c] = red[c] + red[4096 + c] + red[8192 + c] + red[12288 + c];
  float* Mp = Mpart + ((size_t)chunk * 64 + bh) * 256;
  Mp[tid] = margLDS[tid] + margLDS[256 + tid] + margLDS[512 + tid] + margLDS[768 + tid];
}

// ---------------------------------------------------------------------------
// Finalize: sum partials; corr=clip(cov/sqrt(sx sy),0,1); softmax over d;
// store corrT[e][d] bf16. grid 64 (bh), block 64 (e).
// ---------------------------------------------------------------------------
__global__ __launch_bounds__(64) void finalize_k(
    const float* __restrict__ Spart, const float* __restrict__ Mpart,
    u16* __restrict__ corrT)
{
  __shared__ float Ss[4096];
  __shared__ float sqs[64], sxs[64];
  const int bh = blockIdx.x;
  const int e = threadIdx.x;
  for (int idx = e; idx < 4096; idx += 64) {
    float s = 0.f;
#pragma unroll
    for (int c = 0; c < 8; ++c) s += Spart[((size_t)c * 64 + bh) * 4096 + idx];
    Ss[idx] = s;
  }
  float m[4];
#pragma unroll
  for (int p = 0; p < 4; ++p) {
    float s = 0.f;
#pragma unroll
    for (int c = 0; c < 8; ++c) s += Mpart[((size_t)c * 64 + bh) * 256 + p * 64 + e];
    m[p] = s;
  }
  const float invT = 1.0f / 8192.0f;
  const float sy = m[3] - m[2] * m[2] * invT;
  const float ske = m[2];
  sqs[e] = m[0];
  sxs[e] = m[1] - m[0] * m[0] * invT;
  __syncthreads();
  float mx = 0.0f;
  for (int d = 0; d < 64; ++d) {
    const float c = Ss[d * 64 + e] - sqs[d] * ske * invT;
    float r = c / sqrtf(sxs[d] * sy);
    r = fminf(fmaxf(r, 0.0f), 1.0f);
    Ss[d * 64 + e] = r;
    mx = fmaxf(mx, r);
  }
  float sum = 0.f;
  for (int d = 0; d < 64; ++d) {
    const float ev = expf(Ss[d * 64 + e] - mx);
    Ss[d * 64 + e] = ev;
    sum += ev;
  }
  const float inv = 1.0f / sum;
  for (int d = 0; d < 64; ++d)
    corrT[(size_t)bh * 4096 + e * 64 + d] = f2b(Ss[d * 64 + e] * inv);
}

// ---------------------------------------------------------------------------
// Attn: attn[t,e] = sum_d v[t,d]*corr[d,e] per (b,h). A=v natural, B^T=corrT.
// grid = 64 bh * 32 t-tiles(256), block 256.
// ---------------------------------------------------------------------------
__global__ __launch_bounds__(256) void attn_k(
    const u16* __restrict__ vb, const u16* __restrict__ corrT,
    u16* __restrict__ attnb)
{
  __shared__ __align__(16) u16 Vs[256 * 64];
  __shared__ __align__(16) u16 Cs[64 * 64];
  const int tid = threadIdx.x;
  const int bh = blockIdx.x & 63;
  const int tt0 = (blockIdx.x >> 6) * 256;
  const int b = bh >> 4, h = bh & 15;
  const int lane = tid & 63, wave = tid >> 6;
  const int laneN = lane & 15, laneQ = lane >> 4;

  {
#pragma unroll
    for (int i = 0; i < 8; ++i) {
      const int c = tid + i * 256;
      const int row = c >> 3, slot = c & 7;
      const int kb = slot ^ (row & 7);
      const u16* g = vb + (size_t)((tt0 + row) * 4 + b) * 1024 + h * 64 + kb * 8;
      g2l16(g, &Vs[c * 8]);
    }
#pragma unroll
    for (int i = 0; i < 2; ++i) {
      const int c = tid + i * 256;
      const int row = c >> 3, slot = c & 7;
      const int kb = slot ^ (row & 7);
      g2l16(corrT + (size_t)bh * 4096 + row * 64 + kb * 8, &Cs[c * 8]);
    }
  }
  __syncthreads();

  const int wt = wave * 64;
  f32x4 acc[4][4] = {};
#pragma unroll
  for (int ks2 = 0; ks2 < 2; ++ks2) {
    bf16x8 af[4], bf[4];
#pragma unroll
    for (int i = 0; i < 4; ++i) {
      const int row = wt + i * 16 + laneN;
      const int kq = (ks2 * 4 + laneQ) ^ (row & 7);
      af[i] = *(const bf16x8*)&Vs[row * 64 + kq * 8];
    }
#pragma unroll
    for (int j = 0; j < 4; ++j) {
      const int row = j * 16 + laneN;
      const int kq = (ks2 * 4 + laneQ) ^ (row & 7);
      bf[j] = *(const bf16x8*)&Cs[row * 64 + kq * 8];
    }
#pragma unroll
    for (int i = 0; i < 4; ++i)
#pragma unroll
      for (int j = 0; j < 4; ++j)
        acc[i][j] = __builtin_amdgcn_mfma_f32_16x16x32_bf16(af[i], bf[j], acc[i][j], 0, 0, 0);
  }
#pragma unroll
  for (int i = 0; i < 4; ++i)
#pragma unroll
    for (int j = 0; j < 4; ++j)
#pragma unroll
      for (int r = 0; r < 4; ++r) {
        const int t = tt0 + wt + i * 16 + laneQ * 4 + r;
        const int e = j * 16 + laneN;
        attnb[(size_t)(t * 4 + b) * 1024 + h * 64 + e] = f2b(acc[i][j][r]);
      }
}

// ---------------------------------------------------------------------------
// ws layout (bytes):
//   0          qT   [64bh][64][8192] bf16 (64 MiB) -> reused as attn out [32768][1024]
//   67108864   kT   (64 MiB)
//   134217728  vb   [32768][1024] bf16 (64 MiB)
//   201326592  queryb (64 MiB)  -- dead after gemms, aliased by:
//     201326592  Spart 8*64*4096 f32 (8 MiB)
//     209715200  Mpart 8*64*256 f32 (512 KiB)
//     210239488  corrT 64*4096 bf16 (512 KiB)
//   268435456  Wqkvb (6 MiB)
//   274726912  Woutb (2 MiB)
// ---------------------------------------------------------------------------
extern "C" void kernel_launch(void* const* d_in, const int* in_sizes, int n_in,
                              void* d_out, int out_size, void* d_ws, size_t ws_size,
                              hipStream_t stream)
{
  const float* query = (const float*)d_in[0];
  const float* Wqkv  = (const float*)d_in[1];
  const float* bqkv  = (const float*)d_in[2];
  const float* Wout  = (const float*)d_in[3];
  const float* bout  = (const float*)d_in[4];
  char* ws = (char*)d_ws;

  u16*   qkT    = (u16*)(ws);                 // q seg then k seg
  u16*   kT     = (u16*)(ws + 67108864);
  u16*   vb     = (u16*)(ws + 134217728);
  u16*   queryb = (u16*)(ws + 201326592);
  float* Spart  = (float*)(ws + 201326592);
  float* Mpart  = (float*)(ws + 209715200);
  u16*   corrT  = (u16*)(ws + 210239488);
  u16*   Wqkvb  = (u16*)(ws + 268435456);
  u16*   Woutb  = (u16*)(ws + 274726912);

  cvt_all<<<dim3(18432), dim3(256), 0, stream>>>(query, Wqkv, Wout, queryb, Wqkvb, Woutb);

  // q,k features (2048) in swapped orientation -> [bh][d][t] natively
  gemm8p<0><<<dim3(1024), dim3(512), 0, stream>>>(Wqkvb, queryb, bqkv, qkT);
  // v features (1024) in original orientation -> natural [t*4+b][1024]
  gemm8p<1><<<dim3(512), dim3(512), 0, stream>>>(queryb, Wqkvb + (size_t)2048 * 1024,
                                                 bqkv + 2048, vb);
  stats_k<<<dim3(512), dim3(256), 0, stream>>>(qkT, kT, Spart, Mpart);
  finalize_k<<<dim3(64), dim3(64), 0, stream>>>(Spart, Mpart, corrT);
  attn_k<<<dim3(2048), dim3(256), 0, stream>>>(vb, corrT, qkT);
  gemm8p<2><<<dim3(512), dim3(512), 0, stream>>>(qkT, Woutb, bout, d_out);
}